// Round 17
// baseline (35.147 us; speedup 1.0000x reference)
//
#include <hip/hip_runtime.h>
#include <math.h>

// B=4, L=1024, C=128, D=64; rows = B*L = 4096
#define LL   1024
#define NROW 4096
#define DD   64
#define CC   128

// leaky(z) = C1*z + C2*|z|  (slope 0.01)
#define C1H 0.505f
#define C2H 0.495f

typedef short    bf16x8 __attribute__((ext_vector_type(8)));
typedef float    f32x4  __attribute__((ext_vector_type(4)));
typedef _Float16 hf2    __attribute__((ext_vector_type(2)));

#if defined(__has_builtin)
#if __has_builtin(__builtin_amdgcn_fdot2)
#define HAS_FDOT2 1
#endif
#endif

static __device__ __forceinline__ unsigned short bf16rne(float f) {
  unsigned u = __float_as_uint(f);
  u += 0x7fffu + ((u >> 16) & 1u);
  return (unsigned short)(u >> 16);
}

static __device__ __forceinline__ unsigned rflu(unsigned v) {
  return __builtin_amdgcn_readfirstlane(v);
}
static __device__ __forceinline__ float rflf(float v) {
  return __uint_as_float(__builtin_amdgcn_readfirstlane(__float_as_uint(v)));
}

// acc += dot(|gl2 + gr2|, a2)  on packed f16 pairs, f32 accumulate
static __device__ __forceinline__ float dot2abs(unsigned glp, unsigned grp,
                                                unsigned ap, float acc) {
  union { unsigned u; hf2 h; } g1, g2, z, av;
  g1.u = glp; g2.u = grp; av.u = ap;
  z.h = g1.h + g2.h;           // v_pk_add_f16
  z.u &= 0x7fff7fffu;          // packed abs (1 v_and)
#ifdef HAS_FDOT2
  return __builtin_amdgcn_fdot2(z.h, av.h, acc, false);  // v_dot2_f32_f16
#else
  return fmaf((float)z.h.y, (float)av.h.y,
              fmaf((float)z.h.x, (float)av.h.x, acc));
#endif
}

// ---------------------------------------------------------------------------
// k_proj: R16 VERBATIM (validated). 8 rows/block, 256 threads, grid 512.
// grTf frag-major: chunk(b,kc,nt,l)[j] = gr_bf16[d=nt*16+(l&15)][y=kc*32+(l>>4)*8+j]
// ---------------------------------------------------------------------------
__global__ __launch_bounds__(256) void k_proj(
    const float* __restrict__ q, const float* __restrict__ Wl,
    const float* __restrict__ Wr, const float* __restrict__ a,
    uint4* __restrict__ glg, _Float16* __restrict__ gr16,
    unsigned short* __restrict__ grTf,
    float* __restrict__ AL, float* __restrict__ AR) {
  const int bl0 = blockIdx.x * 8;        // 512 blocks, no batch straddle
  const int b = bl0 >> 10;
  const int t = threadIdx.x;
  __shared__ __align__(16) float qs[8 * CC];           // 4 KB
  __shared__ __align__(16) unsigned short trT[DD][8];  // 1 KB
  __shared__ __align__(16) _Float16 trL[8][DD];        // 1 KB

  ((float4*)qs)[t] = ((const float4*)(q + (size_t)bl0 * CC))[t];
  __syncthreads();

  const int rr = t >> 6;                 // 0..3 -> rows rr*2, rr*2+1
  const int d  = t & 63;
  const int r0 = rr * 2, r1 = rr * 2 + 1;
  const float* q0 = qs + r0 * CC;
  const float* q1 = qs + r1 * CC;

  float aL0 = 0, aL1 = 0, aR0 = 0, aR1 = 0;
  float bL0 = 0, bL1 = 0, bR0 = 0, bR1 = 0;
#pragma unroll 8
  for (int c = 0; c < CC; c += 2) {
    float wl0 = Wl[c * DD + d],       wr0 = Wr[c * DD + d];
    float wl1 = Wl[(c + 1) * DD + d], wr1 = Wr[(c + 1) * DD + d];
    aL0 = fmaf(q0[c], wl0, aL0);  bL0 = fmaf(q0[c + 1], wl1, bL0);
    aL1 = fmaf(q1[c], wl0, aL1);  bL1 = fmaf(q1[c + 1], wl1, bL1);
    aR0 = fmaf(q0[c], wr0, aR0);  bR0 = fmaf(q0[c + 1], wr1, bR0);
    aR1 = fmaf(q1[c], wr0, aR1);  bR1 = fmaf(q1[c + 1], wr1, bR1);
  }
  float gL0 = aL0 + bL0, gL1 = aL1 + bL1;
  float gR0 = aR0 + bR0, gR1 = aR1 + bR1;

  trL[r0][d] = (_Float16)gL0;
  trL[r1][d] = (_Float16)gL1;
  gr16[(size_t)(bl0 + r0) * DD + d] = (_Float16)gR0;
  gr16[(size_t)(bl0 + r1) * DD + d] = (_Float16)gR1;
  trT[d][r0] = bf16rne(gR0);
  trT[d][r1] = bf16rne(gR1);

  float av = a[d];
  float vL0 = av * gL0, vL1 = av * gL1, vR0 = av * gR0, vR1 = av * gR1;
#pragma unroll
  for (int off = 1; off < 64; off <<= 1) {
    vL0 += __shfl_xor(vL0, off, 64);
    vL1 += __shfl_xor(vL1, off, 64);
    vR0 += __shfl_xor(vR0, off, 64);
    vR1 += __shfl_xor(vR1, off, 64);
  }
  if (d == 0) {
    AL[bl0 + r0] = vL0; AL[bl0 + r1] = vL1;
    AR[bl0 + r0] = vR0; AR[bl0 + r1] = vR1;
  }
  __syncthreads();
  if (t < 64) {
    // frag-major write: d=t -> nt=d>>4, lane slot l = hi*16 + (d&15), 8 y = 16B
    const int kc = (bl0 & 1023) >> 5;
    const int hi = ((bl0 & 1023) >> 3) & 3;
    ((uint4*)grTf)[((size_t)((b * 32 + kc) * 4 + (t >> 4)) << 6) +
                   hi * 16 + (t & 15)] = *(const uint4*)&trT[t][0];
  } else if (t < 128) {
    int tt = t - 64;
    int r = tt >> 3, g = tt & 7;       // row r, granule g (d = 8g..8g+7)
    glg[(((size_t)(b * 8 + g)) << 10) + (bl0 & 1023) + r] =
        *(const uint4*)&trL[r][g * 8];
  }
}

// ---------------------------------------------------------------------------
// k_fused: 8 x-rows/block, 1024 threads (one y per thread), grid 512.
// 2 blocks/CU x 16 waves = 32 waves/CU = 8 waves/SIMD (was 4). Same total
// work and glg traffic as R16; per-thread work/registers halved.
//  pass 1: gl from glg (coalesced, L2-hot); gr in LDS broadcast; a in SGPRs.
//  softmax: no-max (e bounded), 16-wave partial sums, redundant merge.
//  P: fp32 scores (nontemporal) + packed bf16 frag tile.
//  pass 2: PV via mfma_f32_16x16x32_bf16, 2 kc per wave; B from frag-major
//  grTf (lane-consecutive). Lane maps validated R3-R16.
// ---------------------------------------------------------------------------
__global__ __launch_bounds__(1024, 8) void k_fused(
    const uint4* __restrict__ glg, const _Float16* __restrict__ gr16,
    const unsigned short* __restrict__ grTf,
    const float* __restrict__ AL, const float* __restrict__ AR,
    const float* __restrict__ a,
    float* __restrict__ scores, float* __restrict__ yout) {
  const int bl0 = blockIdx.x * 8;        // 512 blocks
  const int b = bl0 >> 10;
  const int t = threadIdx.x;             // 0..1023 == this thread's y
  const int w = t >> 6, l = t & 63;      // 16 waves

  __shared__ __align__(16) _Float16 grL[8 * DD];        // 1 KB = 256 uints
  __shared__ __align__(16) unsigned short eb[8704];     // 17 KB P frags
  __shared__ __align__(16) float sPV[16][4][8][17];     // 34.8 KB
  __shared__ __align__(16) float sSx[8][16];            // [x][wave]

  // stage gr rows into LDS: 8 rows x 64 f16 = 512 f16 = 256 uints
  if (t < 256)
    ((unsigned*)grL)[t] = ((const unsigned*)(gr16 + (size_t)bl0 * DD))[t];

  // a -> 32 packed-f16 pairs in SGPRs (covers a[0..63])
  unsigned sa[32];
#pragma unroll
  for (int k = 0; k < 16; ++k) {
    float4 av = *(const float4*)&a[k * 4];
    union { hf2 h; unsigned u; } u0, u1;
    u0.h.x = (_Float16)av.x; u0.h.y = (_Float16)av.y;
    u1.h.x = (_Float16)av.z; u1.h.y = (_Float16)av.w;
    sa[k * 2]     = rflu(u0.u);
    sa[k * 2 + 1] = rflu(u1.u);
  }

  float pr[8];
#pragma unroll
  for (int x = 0; x < 8; ++x) pr[x] = C1H * rflf(AR[bl0 + x]);

  const float alv = AL[b * LL + t];      // this thread's y

  float pacc[8];
#pragma unroll
  for (int x = 0; x < 8; ++x) pacc[x] = 0.f;

  __syncthreads();                       // barrier 1: grL ready

  // ---- pass 1: e in registers, dblk-outer (16 d per dblk, 1 y) ----
#pragma unroll
  for (int dblk = 0; dblk < 4; ++dblk) {
    uint4 gv0 = glg[(((size_t)(b * 8 + dblk * 2 + 0)) << 10) + t];
    uint4 gv1 = glg[(((size_t)(b * 8 + dblk * 2 + 1)) << 10) + t];
#pragma unroll
    for (int x = 0; x < 8; ++x) {
      uint4 gra = *(const uint4*)&grL[x * DD + dblk * 16];      // d 0..7
      uint4 grb = *(const uint4*)&grL[x * DD + dblk * 16 + 8];  // d 8..15
      float s = pacc[x];
      s = dot2abs(gv0.x, gra.x, sa[dblk * 8 + 0], s);
      s = dot2abs(gv0.y, gra.y, sa[dblk * 8 + 1], s);
      s = dot2abs(gv0.z, gra.z, sa[dblk * 8 + 2], s);
      s = dot2abs(gv0.w, gra.w, sa[dblk * 8 + 3], s);
      s = dot2abs(gv1.x, grb.x, sa[dblk * 8 + 4], s);
      s = dot2abs(gv1.y, grb.y, sa[dblk * 8 + 5], s);
      s = dot2abs(gv1.z, grb.z, sa[dblk * 8 + 6], s);
      s = dot2abs(gv1.w, grb.w, sa[dblk * 8 + 7], s);
      pacc[x] = s;
    }
  }

  // ---- e -> exp(e) directly (no-max softmax; e bounded ~|8| here) ----
  float ev[8], lsum[8];
#pragma unroll
  for (int x = 0; x < 8; ++x) {
    ev[x] = __expf(fmaf(C2H, pacc[x], pr[x] + C1H * alv));
    lsum[x] = ev[x];
  }
#pragma unroll
  for (int off = 1; off < 64; off <<= 1) {
#pragma unroll
    for (int x = 0; x < 8; ++x) lsum[x] += __shfl_xor(lsum[x], off, 64);
  }
  if (l == 0) {
#pragma unroll
    for (int x = 0; x < 8; ++x) sSx[x][w] = lsum[x];
  }
  __syncthreads();                       // barrier 2

  float isv[8];
#pragma unroll
  for (int x = 0; x < 8; ++x) {
    float4 s0 = *(const float4*)&sSx[x][0];
    float4 s1 = *(const float4*)&sSx[x][4];
    float4 s2 = *(const float4*)&sSx[x][8];
    float4 s3 = *(const float4*)&sSx[x][12];
    isv[x] = 1.0f / ((((s0.x + s0.y) + (s0.z + s0.w)) +
                      ((s1.x + s1.y) + (s1.z + s1.w))) +
                     (((s2.x + s2.y) + (s2.z + s2.w)) +
                      ((s3.x + s3.y) + (s3.z + s3.w))));
  }

  // ---- P writes: fp32 scores (nontemporal) + packed bf16 frag tile ----
  {
    const int kc = t >> 5, k32 = t & 31;
#pragma unroll
    for (int x = 0; x < 8; ++x) {
      float p = ev[x] * isv[x];
      __builtin_nontemporal_store(p, &scores[((size_t)(bl0 + x) << 10) + t]);
      eb[kc * 256 + x * 32 + k32] = bf16rne(p);
    }
  }
  __syncthreads();                       // barrier 3

  // ---- pass 2: PV via MFMA, 32 kc over 16 waves (2 each); coalesced B ----
  f32x4 acc[4] = {{0.f, 0.f, 0.f, 0.f}, {0.f, 0.f, 0.f, 0.f},
                  {0.f, 0.f, 0.f, 0.f}, {0.f, 0.f, 0.f, 0.f}};
  const int row16 = l & 15, hh = l >> 4;
#pragma unroll
  for (int kk = 0; kk < 2; ++kk) {
    int kc = w * 2 + kk;
    bf16x8 af = *(const bf16x8*)&eb[kc * 256 + row16 * 32 + hh * 8];
#pragma unroll
    for (int nt = 0; nt < 4; ++nt) {
      bf16x8 bfv = *(const bf16x8*)(grTf +
          ((((size_t)((b * 32 + kc) * 4 + nt)) << 6) + l) * 8);
      acc[nt] = __builtin_amdgcn_mfma_f32_16x16x32_bf16(af, bfv, acc[nt], 0, 0, 0);
    }
  }
  if (l < 32) {                          // hh 0..1 -> D rows m=hh*4+i (0..7)
#pragma unroll
    for (int nt = 0; nt < 4; ++nt)
#pragma unroll
      for (int i = 0; i < 4; ++i)
        sPV[w][nt][hh * 4 + i][row16] = acc[nt][i];
  }
  __syncthreads();                       // barrier 4
  if (t < 512) {
    int x = t >> 6, dcol = t & 63, nt = dcol >> 4, col = dcol & 15;
    float r = 0.f;
#pragma unroll
    for (int ww = 0; ww < 16; ++ww) r += sPV[ww][nt][x][col];
    yout[(size_t)(bl0 + x) * DD + dcol] = r;
  }
}

// ---------------------------------------------------------------------------
extern "C" void kernel_launch(void* const* d_in, const int* in_sizes, int n_in,
                              void* d_out, int out_size, void* d_ws, size_t ws_size,
                              hipStream_t stream) {
  const float* q  = (const float*)d_in[0];
  // d_in[1] = keys, d_in[2] = values: unused by the reference math
  const float* Wl = (const float*)d_in[3];
  const float* Wr = (const float*)d_in[4];
  const float* a  = (const float*)d_in[5];

  float* yout = (float*)d_out;                 // (4096, 64)
  float* esc  = yout + NROW * DD;              // (4096, 1024) scores

  float* ws = (float*)d_ws;
  float* AL = ws;                               // 4096 f32
  float* AR = AL + NROW;                        // 4096 f32
  uint4* glg = (uint4*)(AR + NROW);             // 4096*8 uint4 (512 KB)
  _Float16* gr16 = (_Float16*)(glg + (size_t)NROW * 8);        // 512 KB
  unsigned short* grTf = (unsigned short*)(gr16 + (size_t)NROW * DD); // 512 KB

  k_proj <<<NROW / 8, 256, 0, stream>>>(q, Wl, Wr, a, glg, gr16, grTf, AL, AR);
  k_fused<<<NROW / 8, 1024, 0, stream>>>(glg, gr16, grTf, AL, AR, a, esc, yout);
}